// Round 1
// 276.385 us; speedup vs baseline: 1.0244x; 1.0244x over previous
//
#include <hip/hip_runtime.h>

#define DIM 1024
#define D4  (DIM / 4)

typedef float vfloat4 __attribute__((ext_vector_type(4)));  // native vec for nontemporal builtins

static __device__ __forceinline__ vfloat4 nt_load4(const vfloat4* p) {
    return __builtin_nontemporal_load(p);   // global_load_dwordx4 ... nt : coherent, no-allocate
}
static __device__ __forceinline__ vfloat4 abs_max4(vfloat4 m, vfloat4 v) {
    m.x = fmaxf(m.x, fabsf(v.x)); m.y = fmaxf(m.y, fabsf(v.y));
    m.z = fmaxf(m.z, fabsf(v.z)); m.w = fmaxf(m.w, fabsf(v.w));
    return m;
}
static __device__ __forceinline__ vfloat4 fq4(vfloat4 x, float sc, float mv) {
    x.x = fminf(fmaxf(rintf(x.x / sc), -mv), mv) * sc;
    x.y = fminf(fmaxf(rintf(x.y / sc), -mv), mv) * sc;
    x.z = fminf(fmaxf(rintf(x.z / sc), -mv), mv) * sc;
    x.w = fminf(fmaxf(rintf(x.w / sc), -mv), mv) * sc;
    return x;
}

// ---------------------------------------------------------------------------
// Pass 1: per-tier abs-max of (tw * ts), tiers 1..3, single launch.
// Round-7 change: per-block maxima published via PLAIN STORES into ws[bid]
// (every slot written -> poison-safe, no zero-init) so the 12-byte
// hipMemsetAsync graph node is deleted (3 nodes -> 2). Fallback (slots==0):
// old atomicMax-into-3-uints protocol, if ws_size is unexpectedly small.
// nt loads, chunked slabs, 8 named accumulators, hoisted |ts| multiply
// (bit-exact: f32 rounding is sign-symmetric and monotone) kept from round 6.
// ---------------------------------------------------------------------------
__global__ __launch_bounds__(256) void absmax3_kernel(
    const vfloat4* __restrict__ tw1, const vfloat4* __restrict__ ts1, long n1,
    const vfloat4* __restrict__ tw2, const vfloat4* __restrict__ ts2, long n2,
    const vfloat4* __restrict__ tw3, const vfloat4* __restrict__ ts3, long n3,
    int b1, int b2, float* __restrict__ ws, int slots)
{
    __shared__ float smax[4];
    int bid = blockIdx.x;
    const vfloat4 *tw, *ts; long n4; int blo, bhi, tier;
    if (bid < b1)      { tw = tw1; ts = ts1; n4 = n1; blo = 0;  bhi = b1;        tier = 0; }
    else if (bid < b2) { tw = tw2; ts = ts2; n4 = n2; blo = b1; bhi = b2;        tier = 1; }
    else               { tw = tw3; ts = ts3; n4 = n3; blo = b2; bhi = gridDim.x; tier = 2; }

    int  nb    = bhi - blo;
    long chunk = (n4 + nb - 1) / nb;
    long start = (long)(bid - blo) * chunk;
    long end   = start + chunk; if (end > n4) end = n4;
    int  t     = threadIdx.x;

    vfloat4 m0 = {0,0,0,0}, m1 = {0,0,0,0}, m2 = {0,0,0,0}, m3 = {0,0,0,0};
    vfloat4 m4 = {0,0,0,0}, m5 = {0,0,0,0}, m6 = {0,0,0,0}, m7 = {0,0,0,0};

    long base = start;
    for (; base + 2048 <= end; base += 2048) {      // 8 x 256 float4 = 32 KB/block/iter
        vfloat4 p0 = nt_load4(tw + base +    0 + t);
        vfloat4 p1 = nt_load4(tw + base +  256 + t);
        vfloat4 p2 = nt_load4(tw + base +  512 + t);
        vfloat4 p3 = nt_load4(tw + base +  768 + t);
        vfloat4 p4 = nt_load4(tw + base + 1024 + t);
        vfloat4 p5 = nt_load4(tw + base + 1280 + t);
        vfloat4 p6 = nt_load4(tw + base + 1536 + t);
        vfloat4 p7 = nt_load4(tw + base + 1792 + t);
        m0 = abs_max4(m0, p0); m1 = abs_max4(m1, p1);
        m2 = abs_max4(m2, p2); m3 = abs_max4(m3, p3);
        m4 = abs_max4(m4, p4); m5 = abs_max4(m5, p5);
        m6 = abs_max4(m6, p6); m7 = abs_max4(m7, p7);
    }
    for (long i = base + t; i < end; i += 256)      // tail, preserves i & 255
        m0 = abs_max4(m0, nt_load4(tw + i));

    m0 = abs_max4(m0, m1); m2 = abs_max4(m2, m3);
    m4 = abs_max4(m4, m5); m6 = abs_max4(m6, m7);
    m0 = abs_max4(m0, m2); m4 = abs_max4(m4, m6);
    m0 = abs_max4(m0, m4);

    vfloat4 s = ts[(start + t) & (D4 - 1)];         // loop-invariant column quad
    float m = fmaxf(fmaxf(m0.x * fabsf(s.x), m0.y * fabsf(s.y)),
                    fmaxf(m0.z * fabsf(s.z), m0.w * fabsf(s.w)));

    for (int off = 32; off > 0; off >>= 1)
        m = fmaxf(m, __shfl_down(m, off));
    if ((threadIdx.x & 63) == 0) smax[threadIdx.x >> 6] = m;
    __syncthreads();
    if (threadIdx.x == 0) {
        float bm = fmaxf(fmaxf(smax[0], smax[1]), fmaxf(smax[2], smax[3]));
        if (slots) ws[bid] = bm;                    // plain store: no init required
        else       atomicMax((unsigned*)ws + tier, __float_as_uint(bm));
    }
}

// ---------------------------------------------------------------------------
// Pass 2: gather + on-the-fly fake-quant.
// Round-7 changes:
//  * block-local segmented max-reduce of the 2048 per-block maxima (8 KB,
//    L3-hot after first touch, ~1-2 us overlapped across 2048 blocks) into
//    LDS -> replaces the memset+atomic handshake.
//  * TWO tokens per wave: 8 independent nt row-loads in flight (was 4),
//    half the wave count -> better latency hiding on the random-row fetch.
// IEEE div + rintf (half-even) match numpy; nontemporal output stores kept.
// ---------------------------------------------------------------------------
__global__ __launch_bounds__(256) void gather_quant_kernel(
    const int* __restrict__ ids, int n_tokens,
    const float* __restrict__ tw0, const float* __restrict__ tw1,
    const float* __restrict__ tw2, const float* __restrict__ tw3,
    const float* __restrict__ ts0, const float* __restrict__ ts1,
    const float* __restrict__ ts2, const float* __restrict__ ts3,
    const float* __restrict__ ws, int nslots, int b1, int b2,
    float* __restrict__ out)
{
    __shared__ float amax_s[3];
    __shared__ float wred[4][3];
    int wid  = threadIdx.x >> 6;
    int lane = threadIdx.x & 63;

    if (nslots > 0) {
        float r0 = 0.f, r1 = 0.f, r2 = 0.f;         // segmented reduce of per-block maxima
        for (int s = threadIdx.x; s < nslots; s += 256) {
            float v = ws[s];
            if      (s < b1) r0 = fmaxf(r0, v);
            else if (s < b2) r1 = fmaxf(r1, v);
            else             r2 = fmaxf(r2, v);
        }
        #pragma unroll
        for (int off = 32; off > 0; off >>= 1) {
            r0 = fmaxf(r0, __shfl_down(r0, off));
            r1 = fmaxf(r1, __shfl_down(r1, off));
            r2 = fmaxf(r2, __shfl_down(r2, off));
        }
        if (lane == 0) { wred[wid][0] = r0; wred[wid][1] = r1; wred[wid][2] = r2; }
        __syncthreads();
        if (threadIdx.x < 3)
            amax_s[threadIdx.x] = fmaxf(fmaxf(wred[0][threadIdx.x], wred[1][threadIdx.x]),
                                        fmaxf(wred[2][threadIdx.x], wred[3][threadIdx.x]));
    } else {
        if (threadIdx.x < 3) amax_s[threadIdx.x] = ws[threadIdx.x];  // atomicMax bits == float bits (nonneg)
    }
    __syncthreads();

    int tA = blockIdx.x * 8 + wid * 2;              // 2 tokens per wave
    int tB = tA + 1;
    bool okA = tA < n_tokens, okB = tB < n_tokens;
    int idA = okA ? ids[tA] : 0;
    int idB = okB ? ids[tB] : 0;

    const float *pA, *pB; const vfloat4 *tsA, *tsB;
    float mvA = 1.f, mvB = 1.f, amA = 1.f, amB = 1.f; bool qA = true, qB = true;

    if (idA < 256)        { pA = tw0 + (long)idA * DIM;           tsA = (const vfloat4*)ts0; qA = false; }
    else if (idA < 2048)  { pA = tw1 + (long)(idA - 256) * DIM;   tsA = (const vfloat4*)ts1; mvA = 127.f; amA = amax_s[0]; }
    else if (idA < 16384) { pA = tw2 + (long)(idA - 2048) * DIM;  tsA = (const vfloat4*)ts2; mvA = 31.f;  amA = amax_s[1]; }
    else                  { pA = tw3 + (long)(idA - 16384) * DIM; tsA = (const vfloat4*)ts3; mvA = 7.f;   amA = amax_s[2]; }

    if (idB < 256)        { pB = tw0 + (long)idB * DIM;           tsB = (const vfloat4*)ts0; qB = false; }
    else if (idB < 2048)  { pB = tw1 + (long)(idB - 256) * DIM;   tsB = (const vfloat4*)ts1; mvB = 127.f; amB = amax_s[0]; }
    else if (idB < 16384) { pB = tw2 + (long)(idB - 2048) * DIM;  tsB = (const vfloat4*)ts2; mvB = 31.f;  amB = amax_s[1]; }
    else                  { pB = tw3 + (long)(idB - 16384) * DIM; tsB = (const vfloat4*)ts3; mvB = 7.f;   amB = amax_s[2]; }

    const vfloat4* wvA = (const vfloat4*)pA + lane;
    const vfloat4* wvB = (const vfloat4*)pB + lane;
    // issue all 8 row loads before any consumption
    vfloat4 a0 = nt_load4(wvA +   0), a1 = nt_load4(wvA +  64);
    vfloat4 a2 = nt_load4(wvA + 128), a3 = nt_load4(wvA + 192);
    vfloat4 c0 = nt_load4(wvB +   0), c1 = nt_load4(wvB +  64);
    vfloat4 c2 = nt_load4(wvB + 128), c3 = nt_load4(wvB + 192);
    vfloat4 sA0 = tsA[lane +   0], sA1 = tsA[lane +  64];       // cached: hot in L1/L2
    vfloat4 sA2 = tsA[lane + 128], sA3 = tsA[lane + 192];
    vfloat4 sB0 = tsB[lane +   0], sB1 = tsB[lane +  64];
    vfloat4 sB2 = tsB[lane + 128], sB3 = tsB[lane + 192];

    float scA = fmaxf(amA, 1e-8f) / mvA;
    float scB = fmaxf(amB, 1e-8f) / mvB;

    if (okA) {
        vfloat4* op = (vfloat4*)(out + (long)tA * DIM) + lane;
        vfloat4 x0 = a0 * sA0, x1 = a1 * sA1, x2 = a2 * sA2, x3 = a3 * sA3;
        if (qA) { x0 = fq4(x0, scA, mvA); x1 = fq4(x1, scA, mvA);
                  x2 = fq4(x2, scA, mvA); x3 = fq4(x3, scA, mvA); }
        __builtin_nontemporal_store(x0, op +   0);
        __builtin_nontemporal_store(x1, op +  64);
        __builtin_nontemporal_store(x2, op + 128);
        __builtin_nontemporal_store(x3, op + 192);
    }
    if (okB) {
        vfloat4* op = (vfloat4*)(out + (long)tB * DIM) + lane;
        vfloat4 x0 = c0 * sB0, x1 = c1 * sB1, x2 = c2 * sB2, x3 = c3 * sB3;
        if (qB) { x0 = fq4(x0, scB, mvB); x1 = fq4(x1, scB, mvB);
                  x2 = fq4(x2, scB, mvB); x3 = fq4(x3, scB, mvB); }
        __builtin_nontemporal_store(x0, op +   0);
        __builtin_nontemporal_store(x1, op +  64);
        __builtin_nontemporal_store(x2, op + 128);
        __builtin_nontemporal_store(x3, op + 192);
    }
}

extern "C" void kernel_launch(void* const* d_in, const int* in_sizes, int n_in,
                              void* d_out, int out_size, void* d_ws, size_t ws_size,
                              hipStream_t stream) {
    const int*   ids = (const int*)d_in[0];
    const float* tw0 = (const float*)d_in[1];
    const float* tw1 = (const float*)d_in[2];
    const float* tw2 = (const float*)d_in[3];
    const float* tw3 = (const float*)d_in[4];
    const float* ts0 = (const float*)d_in[5];
    const float* ts1 = (const float*)d_in[6];
    const float* ts2 = (const float*)d_in[7];
    const float* ts3 = (const float*)d_in[8];
    float* out = (float*)d_out;

    long n1 = (long)in_sizes[2] / 4;     // float4 counts
    long n2 = (long)in_sizes[3] / 4;
    long n3 = (long)in_sizes[4] / 4;
    long N  = n1 + n2 + n3;

    const int G = 2048;                  // 8 blocks/CU, fully resident
    int b1 = (int)((n1 * G + N - 1) / N); if (b1 < 1) b1 = 1;
    int b2 = b1 + (int)((n2 * G) / N);    if (b2 <= b1) b2 = b1 + 1;
    if (b2 >= G) b2 = G - 1;

    // per-block-slot protocol (no memset node) when workspace allows; else
    // fall back to the proven 3-uint atomicMax protocol.
    int use_slots = (ws_size >= (size_t)G * sizeof(float)) ? 1 : 0;
    if (!use_slots)
        (void)hipMemsetAsync(d_ws, 0, 3 * sizeof(unsigned), stream);

    absmax3_kernel<<<G, 256, 0, stream>>>(
        (const vfloat4*)tw1, (const vfloat4*)ts1, n1,
        (const vfloat4*)tw2, (const vfloat4*)ts2, n2,
        (const vfloat4*)tw3, (const vfloat4*)ts3, n3,
        b1, b2, (float*)d_ws, use_slots);

    int n_tokens = in_sizes[0];          // 16384
    gather_quant_kernel<<<(n_tokens + 7) / 8, 256, 0, stream>>>(
        ids, n_tokens, tw0, tw1, tw2, tw3, ts0, ts1, ts2, ts3,
        (const float*)d_ws, use_slots ? G : 0, b1, b2, out);
}

// Round 2
// 268.861 us; speedup vs baseline: 1.0530x; 1.0280x over previous
//
#include <hip/hip_runtime.h>

#define DIM 1024
#define D4  (DIM / 4)

typedef float vfloat4 __attribute__((ext_vector_type(4)));  // native vec for nontemporal builtins

static __device__ __forceinline__ vfloat4 nt_load4(const vfloat4* p) {
    return __builtin_nontemporal_load(p);   // global_load_dwordx4 ... nt : coherent, no-allocate
}
static __device__ __forceinline__ vfloat4 abs_max4(vfloat4 m, vfloat4 v) {
    m.x = fmaxf(m.x, fabsf(v.x)); m.y = fmaxf(m.y, fabsf(v.y));
    m.z = fmaxf(m.z, fabsf(v.z)); m.w = fmaxf(m.w, fabsf(v.w));
    return m;
}
static __device__ __forceinline__ vfloat4 fq4(vfloat4 x, float sc, float mv) {
    x.x = fminf(fmaxf(rintf(x.x / sc), -mv), mv) * sc;
    x.y = fminf(fmaxf(rintf(x.y / sc), -mv), mv) * sc;
    x.z = fminf(fmaxf(rintf(x.z / sc), -mv), mv) * sc;
    x.w = fminf(fmaxf(rintf(x.w / sc), -mv), mv) * sc;
    return x;
}

// ---------------------------------------------------------------------------
// Pass 1: per-tier abs-max of (tw * ts), tiers 1..3, single launch.
// Unchanged from round 7 (verified): per-block maxima via plain stores into
// ws[bid] (every slot written -> poison-safe, no zero-init node). Fallback
// (slots==0): atomicMax-into-3-uints + host memset. nt loads, chunked slabs,
// 8 named accumulators, hoisted |ts| multiply (bit-exact: f32 rounding is
// sign-symmetric and monotone).
// ---------------------------------------------------------------------------
__global__ __launch_bounds__(256) void absmax3_kernel(
    const vfloat4* __restrict__ tw1, const vfloat4* __restrict__ ts1, long n1,
    const vfloat4* __restrict__ tw2, const vfloat4* __restrict__ ts2, long n2,
    const vfloat4* __restrict__ tw3, const vfloat4* __restrict__ ts3, long n3,
    int b1, int b2, float* __restrict__ ws, int slots)
{
    __shared__ float smax[4];
    int bid = blockIdx.x;
    const vfloat4 *tw, *ts; long n4; int blo, bhi, tier;
    if (bid < b1)      { tw = tw1; ts = ts1; n4 = n1; blo = 0;  bhi = b1;        tier = 0; }
    else if (bid < b2) { tw = tw2; ts = ts2; n4 = n2; blo = b1; bhi = b2;        tier = 1; }
    else               { tw = tw3; ts = ts3; n4 = n3; blo = b2; bhi = gridDim.x; tier = 2; }

    int  nb    = bhi - blo;
    long chunk = (n4 + nb - 1) / nb;
    long start = (long)(bid - blo) * chunk;
    long end   = start + chunk; if (end > n4) end = n4;
    int  t     = threadIdx.x;

    vfloat4 m0 = {0,0,0,0}, m1 = {0,0,0,0}, m2 = {0,0,0,0}, m3 = {0,0,0,0};
    vfloat4 m4 = {0,0,0,0}, m5 = {0,0,0,0}, m6 = {0,0,0,0}, m7 = {0,0,0,0};

    long base = start;
    for (; base + 2048 <= end; base += 2048) {      // 8 x 256 float4 = 32 KB/block/iter
        vfloat4 p0 = nt_load4(tw + base +    0 + t);
        vfloat4 p1 = nt_load4(tw + base +  256 + t);
        vfloat4 p2 = nt_load4(tw + base +  512 + t);
        vfloat4 p3 = nt_load4(tw + base +  768 + t);
        vfloat4 p4 = nt_load4(tw + base + 1024 + t);
        vfloat4 p5 = nt_load4(tw + base + 1280 + t);
        vfloat4 p6 = nt_load4(tw + base + 1536 + t);
        vfloat4 p7 = nt_load4(tw + base + 1792 + t);
        m0 = abs_max4(m0, p0); m1 = abs_max4(m1, p1);
        m2 = abs_max4(m2, p2); m3 = abs_max4(m3, p3);
        m4 = abs_max4(m4, p4); m5 = abs_max4(m5, p5);
        m6 = abs_max4(m6, p6); m7 = abs_max4(m7, p7);
    }
    for (long i = base + t; i < end; i += 256)      // tail, preserves i & 255
        m0 = abs_max4(m0, nt_load4(tw + i));

    m0 = abs_max4(m0, m1); m2 = abs_max4(m2, m3);
    m4 = abs_max4(m4, m5); m6 = abs_max4(m6, m7);
    m0 = abs_max4(m0, m2); m4 = abs_max4(m4, m6);
    m0 = abs_max4(m0, m4);

    vfloat4 s = ts[(start + t) & (D4 - 1)];         // loop-invariant column quad
    float m = fmaxf(fmaxf(m0.x * fabsf(s.x), m0.y * fabsf(s.y)),
                    fmaxf(m0.z * fabsf(s.z), m0.w * fabsf(s.w)));

    for (int off = 32; off > 0; off >>= 1)
        m = fmaxf(m, __shfl_down(m, off));
    if ((threadIdx.x & 63) == 0) smax[threadIdx.x >> 6] = m;
    __syncthreads();
    if (threadIdx.x == 0) {
        float bm = fmaxf(fmaxf(smax[0], smax[1]), fmaxf(smax[2], smax[3]));
        if (slots) ws[bid] = bm;                    // plain store: no init required
        else       atomicMax((unsigned*)ws + tier, __float_as_uint(bm));
    }
}

// ---------------------------------------------------------------------------
// Pass 2: gather + on-the-fly fake-quant.
// Round-8 restructure (latency hiding):
//  Phase A: read ids, ISSUE ALL 16 nt row-loads (4 tokens/wave) first.
//  Phase B: segmented ws amax-reduce runs while those loads are in flight.
//  Phase C: consume, quantize, nt-store.
// 4 tokens/wave -> 1024 blocks: halves the redundant per-block ws reduces.
// __launch_bounds__(256,4): VGPR<=128 so the 16 in-flight float4 don't spill.
// IEEE div + rintf (half-even) match numpy; nontemporal output stores kept.
// ---------------------------------------------------------------------------
__global__ __launch_bounds__(256, 4) void gather_quant_kernel(
    const int* __restrict__ ids, int n_tokens,
    const float* __restrict__ tw0, const float* __restrict__ tw1,
    const float* __restrict__ tw2, const float* __restrict__ tw3,
    const float* __restrict__ ts0, const float* __restrict__ ts1,
    const float* __restrict__ ts2, const float* __restrict__ ts3,
    const float* __restrict__ ws, int nslots, int b1, int b2,
    float* __restrict__ out)
{
    __shared__ float amax_s[3];
    __shared__ float wred[4][3];
    int wid  = threadIdx.x >> 6;
    int lane = threadIdx.x & 63;
    int tok0 = blockIdx.x * 16 + wid * 4;           // 4 tokens per wave

    // ---- Phase A: resolve rows and issue all 16 row loads ----
    const vfloat4* tsv[4];
    float mv[4]; int amix[4]; bool ok[4];
    vfloat4 v[4][4];
    const vfloat4* rowp[4];
    #pragma unroll
    for (int i = 0; i < 4; ++i) {
        int tok = tok0 + i;
        ok[i] = tok < n_tokens;
        int id = ok[i] ? ids[tok] : 0;
        const float* p;
        if (id < 256)        { p = tw0 + (long)id * DIM;           tsv[i] = (const vfloat4*)ts0; mv[i] = 1.f;   amix[i] = -1; }
        else if (id < 2048)  { p = tw1 + (long)(id - 256) * DIM;   tsv[i] = (const vfloat4*)ts1; mv[i] = 127.f; amix[i] = 0; }
        else if (id < 16384) { p = tw2 + (long)(id - 2048) * DIM;  tsv[i] = (const vfloat4*)ts2; mv[i] = 31.f;  amix[i] = 1; }
        else                 { p = tw3 + (long)(id - 16384) * DIM; tsv[i] = (const vfloat4*)ts3; mv[i] = 7.f;   amix[i] = 2; }
        rowp[i] = (const vfloat4*)p + lane;
    }
    #pragma unroll
    for (int i = 0; i < 4; ++i) {
        v[i][0] = nt_load4(rowp[i] +   0);
        v[i][1] = nt_load4(rowp[i] +  64);
        v[i][2] = nt_load4(rowp[i] + 128);
        v[i][3] = nt_load4(rowp[i] + 192);
    }

    // ---- Phase B: amax reduce overlaps the in-flight row loads ----
    if (nslots > 0) {
        float r0 = 0.f, r1 = 0.f, r2 = 0.f;         // segmented reduce of per-block maxima
        for (int s = threadIdx.x; s < nslots; s += 256) {
            float x = ws[s];
            if      (s < b1) r0 = fmaxf(r0, x);
            else if (s < b2) r1 = fmaxf(r1, x);
            else             r2 = fmaxf(r2, x);
        }
        #pragma unroll
        for (int off = 32; off > 0; off >>= 1) {
            r0 = fmaxf(r0, __shfl_down(r0, off));
            r1 = fmaxf(r1, __shfl_down(r1, off));
            r2 = fmaxf(r2, __shfl_down(r2, off));
        }
        if (lane == 0) { wred[wid][0] = r0; wred[wid][1] = r1; wred[wid][2] = r2; }
        __syncthreads();
        if (threadIdx.x < 3)
            amax_s[threadIdx.x] = fmaxf(fmaxf(wred[0][threadIdx.x], wred[1][threadIdx.x]),
                                        fmaxf(wred[2][threadIdx.x], wred[3][threadIdx.x]));
    } else {
        if (threadIdx.x < 3) amax_s[threadIdx.x] = ws[threadIdx.x];  // atomicMax bits == float bits (nonneg)
    }
    __syncthreads();

    // ---- Phase C: consume, quantize, store ----
    #pragma unroll
    for (int i = 0; i < 4; ++i) {
        if (!ok[i]) continue;
        vfloat4 s0 = tsv[i][lane +   0], s1 = tsv[i][lane +  64];   // L1/L2-hot
        vfloat4 s2 = tsv[i][lane + 128], s3 = tsv[i][lane + 192];
        vfloat4 x0 = v[i][0] * s0, x1 = v[i][1] * s1;
        vfloat4 x2 = v[i][2] * s2, x3 = v[i][3] * s3;
        if (amix[i] >= 0) {
            float sc = fmaxf(amax_s[amix[i]], 1e-8f) / mv[i];
            x0 = fq4(x0, sc, mv[i]); x1 = fq4(x1, sc, mv[i]);
            x2 = fq4(x2, sc, mv[i]); x3 = fq4(x3, sc, mv[i]);
        }
        vfloat4* op = (vfloat4*)(out + (long)(tok0 + i) * DIM) + lane;
        __builtin_nontemporal_store(x0, op +   0);
        __builtin_nontemporal_store(x1, op +  64);
        __builtin_nontemporal_store(x2, op + 128);
        __builtin_nontemporal_store(x3, op + 192);
    }
}

extern "C" void kernel_launch(void* const* d_in, const int* in_sizes, int n_in,
                              void* d_out, int out_size, void* d_ws, size_t ws_size,
                              hipStream_t stream) {
    const int*   ids = (const int*)d_in[0];
    const float* tw0 = (const float*)d_in[1];
    const float* tw1 = (const float*)d_in[2];
    const float* tw2 = (const float*)d_in[3];
    const float* tw3 = (const float*)d_in[4];
    const float* ts0 = (const float*)d_in[5];
    const float* ts1 = (const float*)d_in[6];
    const float* ts2 = (const float*)d_in[7];
    const float* ts3 = (const float*)d_in[8];
    float* out = (float*)d_out;

    long n1 = (long)in_sizes[2] / 4;     // float4 counts
    long n2 = (long)in_sizes[3] / 4;
    long n3 = (long)in_sizes[4] / 4;
    long N  = n1 + n2 + n3;

    const int G = 2048;                  // 8 blocks/CU, fully resident
    int b1 = (int)((n1 * G + N - 1) / N); if (b1 < 1) b1 = 1;
    int b2 = b1 + (int)((n2 * G) / N);    if (b2 <= b1) b2 = b1 + 1;
    if (b2 >= G) b2 = G - 1;

    // per-block-slot protocol (no memset node) when workspace allows; else
    // fall back to the proven 3-uint atomicMax protocol.
    int use_slots = (ws_size >= (size_t)G * sizeof(float)) ? 1 : 0;
    if (!use_slots)
        (void)hipMemsetAsync(d_ws, 0, 3 * sizeof(unsigned), stream);

    absmax3_kernel<<<G, 256, 0, stream>>>(
        (const vfloat4*)tw1, (const vfloat4*)ts1, n1,
        (const vfloat4*)tw2, (const vfloat4*)ts2, n2,
        (const vfloat4*)tw3, (const vfloat4*)ts3, n3,
        b1, b2, (float*)d_ws, use_slots);

    int n_tokens = in_sizes[0];          // 16384
    gather_quant_kernel<<<(n_tokens + 15) / 16, 256, 0, stream>>>(
        ids, n_tokens, tw0, tw1, tw2, tw3, ts0, ts1, ts2, ts3,
        (const float*)d_ws, use_slots ? G : 0, b1, b2, out);
}